// Round 2
// baseline (732.042 us; speedup 1.0000x reference)
//
#include <hip/hip_runtime.h>

// GNN layer (all fp32 buffers):
//   out = (embed + L@embed) @ W1^T + b1 + (L@embed^2) @ W2^T + b2
//   L = D^-1/2 A D^-1/2, A = 2M COO edges (row, col), N=144242, D=64.
// Device-side CSR build (count -> scan -> fill), then fused
// gather-SpMM + double-linear. One wave per node, lane = feature dim.

__global__ void k_deg(const int* __restrict__ row, int* __restrict__ deg, int E) {
    int e = blockIdx.x * blockDim.x + threadIdx.x;
    if (e < E) atomicAdd(&deg[row[e]], 1);
}

__global__ void k_dinv(const int* __restrict__ deg, float* __restrict__ dinv, int n) {
    int i = blockIdx.x * blockDim.x + threadIdx.x;
    if (i < n) {
        int d = deg[i];
        dinv[i] = d > 0 ? rsqrtf((float)d) : 0.0f;
    }
}

// Exclusive scan of deg -> per-element partials + per-block sums (1024 elems/block)
__global__ void k_scan1(const int* __restrict__ deg, int* __restrict__ part,
                        int* __restrict__ bsums, int n) {
    __shared__ int lds[256];
    int t = threadIdx.x;
    int base = blockIdx.x * 1024 + t * 4;
    int v0 = (base + 0 < n) ? deg[base + 0] : 0;
    int v1 = (base + 1 < n) ? deg[base + 1] : 0;
    int v2 = (base + 2 < n) ? deg[base + 2] : 0;
    int v3 = (base + 3 < n) ? deg[base + 3] : 0;
    int s = v0 + v1 + v2 + v3;
    lds[t] = s;
    __syncthreads();
    for (int off = 1; off < 256; off <<= 1) {
        int x = (t >= off) ? lds[t - off] : 0;
        __syncthreads();
        lds[t] += x;
        __syncthreads();
    }
    int excl = lds[t] - s;
    if (t == 255) bsums[blockIdx.x] = lds[255];
    int run = excl;
    if (base + 0 < n) { part[base + 0] = run; run += v0; }
    if (base + 1 < n) { part[base + 1] = run; run += v1; }
    if (base + 2 < n) { part[base + 2] = run; run += v2; }
    if (base + 3 < n) { part[base + 3] = run; }
}

__global__ void k_scan2(int* bsums, int nblk) {
    if (threadIdx.x == 0 && blockIdx.x == 0) {
        int s = 0;
        for (int k = 0; k < nblk; k++) { int t = bsums[k]; bsums[k] = s; s += t; }
    }
}

__global__ void k_scan3(const int* __restrict__ part, const int* __restrict__ bsums,
                        int* __restrict__ start, int* __restrict__ cursor, int n, int E) {
    int i = blockIdx.x * blockDim.x + threadIdx.x;
    if (i < n) {
        int s = part[i] + bsums[i >> 10];
        start[i] = s;
        cursor[i] = s;
    }
    if (i == 0) start[n] = E;
}

__global__ void k_fill(const int* __restrict__ row, const int* __restrict__ col,
                       int* __restrict__ cursor, int* __restrict__ scol, int E) {
    int e = blockIdx.x * blockDim.x + threadIdx.x;
    if (e < E) {
        int r = row[e];
        int pos = atomicAdd(&cursor[r], 1);
        scol[pos] = col[e];
    }
}

// Fused: per-node gather SpMM (h1, h2) + [h1 h2] @ [W1;W2]^T + b1 + b2
__global__ __launch_bounds__(256) void k_main(
    const float* __restrict__ embed,
    const int* __restrict__ start,
    const int* __restrict__ scol,
    const float* __restrict__ dinv,
    const float* __restrict__ W1,
    const float* __restrict__ b1,
    const float* __restrict__ W2,
    const float* __restrict__ b2,
    float* __restrict__ out, int n) {
    // wB[k*64+d] = (W1[d][k], W2[d][k]) : transposed so lane-d reads are 2-way
    // bank-aliased (free on CDNA4 per m136), h reads are uniform broadcast.
    __shared__ float2 wB[64 * 64];
    __shared__ float2 hbuf[4][64];
    int tid = threadIdx.x;
    for (int idx = tid; idx < 4096; idx += 256) {
        int d = idx >> 6, k = idx & 63;
        wB[(k << 6) + d] = make_float2(W1[idx], W2[idx]);
    }
    __syncthreads();

    int wave = tid >> 6, lane = tid & 63;
    int i = blockIdx.x * 4 + wave;
    bool valid = i < n;

    float dv = 0.0f, e0 = 0.0f;
    int s0 = 0, s1 = 0;
    if (valid) {
        dv = dinv[i];
        e0 = embed[(i << 6) + lane];
        s0 = start[i];
        s1 = start[i + 1];
    }

    float acc1 = 0.0f, acc2 = 0.0f;
    for (int e = s0; e < s1;) {
        int cnt = s1 - e;
        if (cnt > 64) cnt = 64;
        // batch-load up to 64 neighbor ids + their dinv, broadcast via shfl
        int jv = (lane < cnt) ? scol[e + lane] : 0;
        float dj = (lane < cnt) ? dinv[jv] : 0.0f;
        for (int k = 0; k < cnt; k++) {
            int j = __shfl(jv, k, 64);
            float val = dv * __shfl(dj, k, 64);
            float x = embed[(j << 6) + lane];
            acc1 = fmaf(val, x, acc1);
            acc2 = fmaf(val * x, x, acc2);
        }
        e += cnt;
    }

    hbuf[wave][lane] = make_float2(e0 + acc1, acc2);
    __syncthreads();

    if (valid) {
        float acc = b1[lane] + b2[lane];
#pragma unroll
        for (int k = 0; k < 64; k++) {
            float2 h = hbuf[wave][k];
            float2 w = wB[(k << 6) + lane];
            acc = fmaf(h.x, w.x, acc);
            acc = fmaf(h.y, w.y, acc);
        }
        out[(i << 6) + lane] = acc;
    }
}

extern "C" void kernel_launch(void* const* d_in, const int* in_sizes, int n_in,
                              void* d_out, int out_size, void* d_ws, size_t ws_size,
                              hipStream_t stream) {
    const float* embed = (const float*)d_in[0];
    const int* row = (const int*)d_in[1];
    const int* col = (const int*)d_in[2];
    const float* W1 = (const float*)d_in[3];
    const float* b1 = (const float*)d_in[4];
    const float* W2 = (const float*)d_in[5];
    const float* b2 = (const float*)d_in[6];
    float* out = (float*)d_out;

    int n = in_sizes[0] / 64;   // 144242
    int E = in_sizes[1];        // 2,000,000
    int nblk = (n + 1023) / 1024;

    char* ws = (char*)d_ws;
    size_t off = 0;
    int* deg = (int*)(ws + off);      off += (size_t)n * 4;
    float* dinv = (float*)(ws + off); off += (size_t)n * 4;
    int* part = (int*)(ws + off);     off += (size_t)n * 4;
    int* bsums = (int*)(ws + off);    off += (size_t)(nblk + 1) * 4;
    int* start = (int*)(ws + off);    off += (size_t)(n + 1) * 4;
    int* cursor = (int*)(ws + off);   off += (size_t)n * 4;
    int* scol = (int*)(ws + off);     off += (size_t)E * 4;

    if (off > ws_size) return;  // ws too small -> leave out zeroed (visible as 0.707 absmax)

    hipMemsetAsync(deg, 0, (size_t)n * 4, stream);
    k_deg<<<(E + 255) / 256, 256, 0, stream>>>(row, deg, E);
    k_dinv<<<(n + 255) / 256, 256, 0, stream>>>(deg, dinv, n);
    k_scan1<<<nblk, 256, 0, stream>>>(deg, part, bsums, n);
    k_scan2<<<1, 64, 0, stream>>>(bsums, nblk);
    k_scan3<<<(n + 255) / 256, 256, 0, stream>>>(part, bsums, start, cursor, n, E);
    k_fill<<<(E + 255) / 256, 256, 0, stream>>>(row, col, cursor, scol, E);
    k_main<<<(n + 3) / 4, 256, 0, stream>>>(embed, start, scol, dinv, W1, b1, W2, b2, out, n);
}

// Round 3
// 387.226 us; speedup vs baseline: 1.8905x; 1.8905x over previous
//
#include <hip/hip_runtime.h>

// GNN layer (fp32):
//   out = (embed + L@embed) @ W1^T + b1 + (L@embed^2) @ W2^T + b2
//   L = D^-1/2 A D^-1/2, A = 2M COO edges, N=144242, D=64.
// CSR build (count -> scan -> fill w/ precomputed edge vals) then fused
// gather-SpMM + double-linear. One wave per node; 4x16-lane groups give
// 4 neighbor rows per load instruction (MLP), float4 per lane.

struct HPair { float4 h1, h2; };

__global__ void k_deg(const int* __restrict__ row, int* __restrict__ deg, int E) {
    int e = blockIdx.x * blockDim.x + threadIdx.x;
    if (e < E) atomicAdd(&deg[row[e]], 1);
}

// dinv + one-time transposed/interleaved weight buffer wBg[k*64+d]={W1[d][k],W2[d][k]}
__global__ void k_dinv_wprep(const int* __restrict__ deg, float* __restrict__ dinv,
                             const float* __restrict__ W1, const float* __restrict__ W2,
                             float2* __restrict__ wBg, int n) {
    int i = blockIdx.x * blockDim.x + threadIdx.x;
    if (i < n) {
        int d = deg[i];
        dinv[i] = d > 0 ? rsqrtf((float)d) : 0.0f;
    }
    if (i < 4096) {
        int d = i >> 6, k = i & 63;
        wBg[(k << 6) + d] = make_float2(W1[i], W2[i]);
    }
}

// Exclusive scan of deg (1024 elems/block)
__global__ void k_scan1(const int* __restrict__ deg, int* __restrict__ part,
                        int* __restrict__ bsums, int n) {
    __shared__ int lds[256];
    int t = threadIdx.x;
    int base = blockIdx.x * 1024 + t * 4;
    int v0 = (base + 0 < n) ? deg[base + 0] : 0;
    int v1 = (base + 1 < n) ? deg[base + 1] : 0;
    int v2 = (base + 2 < n) ? deg[base + 2] : 0;
    int v3 = (base + 3 < n) ? deg[base + 3] : 0;
    int s = v0 + v1 + v2 + v3;
    lds[t] = s;
    __syncthreads();
    for (int off = 1; off < 256; off <<= 1) {
        int x = (t >= off) ? lds[t - off] : 0;
        __syncthreads();
        lds[t] += x;
        __syncthreads();
    }
    int excl = lds[t] - s;
    if (t == 255) bsums[blockIdx.x] = lds[255];
    int run = excl;
    if (base + 0 < n) { part[base + 0] = run; run += v0; }
    if (base + 1 < n) { part[base + 1] = run; run += v1; }
    if (base + 2 < n) { part[base + 2] = run; run += v2; }
    if (base + 3 < n) { part[base + 3] = run; }
}

__global__ void k_scan2(int* bsums, int nblk) {
    if (threadIdx.x == 0 && blockIdx.x == 0) {
        int s = 0;
        for (int k = 0; k < nblk; k++) { int t = bsums[k]; bsums[k] = s; s += t; }
    }
}

__global__ void k_scan3(const int* __restrict__ part, const int* __restrict__ bsums,
                        int* __restrict__ start, int* __restrict__ cursor, int n, int E) {
    int i = blockIdx.x * blockDim.x + threadIdx.x;
    if (i < n) {
        int s = part[i] + bsums[i >> 10];
        start[i] = s;
        cursor[i] = s;
    }
    if (i == 0) start[n] = E;
}

// fill CSR with precomputed edge value: sedge[pos] = {col, bits(dinv[r]*dinv[c])}
__global__ void k_fill(const int* __restrict__ row, const int* __restrict__ col,
                       const float* __restrict__ dinv, int* __restrict__ cursor,
                       int2* __restrict__ sedge, int E) {
    int e = blockIdx.x * blockDim.x + threadIdx.x;
    if (e < E) {
        int r = row[e], c = col[e];
        float v = dinv[r] * dinv[c];
        int pos = atomicAdd(&cursor[r], 1);
        sedge[pos] = make_int2(c, __float_as_int(v));
    }
}

// Fused gather-SpMM + double-linear. 8 waves/block, 1 node/wave.
__global__ __launch_bounds__(512, 6) void k_main(
    const float4* __restrict__ embed4,
    const int* __restrict__ start,
    const int2* __restrict__ sedge,
    const float2* __restrict__ wBg,
    const float* __restrict__ b1,
    const float* __restrict__ b2,
    float* __restrict__ out, int n) {
    __shared__ float2 wB[4096];      // wB[k*64+d] = (W1[d][k], W2[d][k])
    __shared__ HPair hbuf[8][16];
    int tid = threadIdx.x;
    {   // conflict-free staging: coalesced global read -> linear LDS write
        const float4* src = (const float4*)wBg;
        float4* dst = (float4*)wB;
#pragma unroll
        for (int t = 0; t < 4; t++) dst[tid + 512 * t] = src[tid + 512 * t];
    }
    __syncthreads();

    int wave = tid >> 6, lane = tid & 63;
    int g = lane >> 4, l = lane & 15;
    int i = blockIdx.x * 8 + wave;
    bool valid = i < n;
    int ii = valid ? i : 0;

    int s0 = start[ii];
    int s1 = valid ? start[ii + 1] : 0;
    float4 ev = embed4[(size_t)ii * 16 + l];   // own row (same for all 4 groups)

    float4 a1 = make_float4(0.f, 0.f, 0.f, 0.f);
    float4 a2 = make_float4(0.f, 0.f, 0.f, 0.f);

#define CHUNK(T) { \
        int t_ = (T) + g; \
        int src_ = t_ < cnt ? t_ : 0; \
        int j_ = __shfl(jv, src_, 64); \
        float v_ = __shfl(vv, src_, 64); \
        v_ = t_ < cnt ? v_ : 0.0f; \
        float4 x_ = embed4[(size_t)j_ * 16 + l]; \
        a1.x = fmaf(v_, x_.x, a1.x); a1.y = fmaf(v_, x_.y, a1.y); \
        a1.z = fmaf(v_, x_.z, a1.z); a1.w = fmaf(v_, x_.w, a1.w); \
        a2.x = fmaf(v_ * x_.x, x_.x, a2.x); a2.y = fmaf(v_ * x_.y, x_.y, a2.y); \
        a2.z = fmaf(v_ * x_.z, x_.z, a2.z); a2.w = fmaf(v_ * x_.w, x_.w, a2.w); \
    }

    for (int e = s0; e < s1;) {
        int cnt = s1 - e;
        if (cnt > 64) cnt = 64;
        int2 ed = sedge[e + (lane < cnt ? lane : 0)];  // batch of ids+vals
        int jv = ed.x;
        float vv = __int_as_float(ed.y);
        for (int kk = 0; kk < cnt; kk += 8) { CHUNK(kk) CHUNK(kk + 4) }
        e += cnt;
    }
#undef CHUNK

    // combine the 4 groups' partials (lanes differing in bits 4,5)
#pragma unroll
    for (int m = 16; m <= 32; m <<= 1) {
        a1.x += __shfl_xor(a1.x, m, 64); a1.y += __shfl_xor(a1.y, m, 64);
        a1.z += __shfl_xor(a1.z, m, 64); a1.w += __shfl_xor(a1.w, m, 64);
        a2.x += __shfl_xor(a2.x, m, 64); a2.y += __shfl_xor(a2.y, m, 64);
        a2.z += __shfl_xor(a2.z, m, 64); a2.w += __shfl_xor(a2.w, m, 64);
    }
    if (lane < 16) {
        hbuf[wave][l].h1 = make_float4(a1.x + ev.x, a1.y + ev.y, a1.z + ev.z, a1.w + ev.w);
        hbuf[wave][l].h2 = a2;
    }
    // wave-internal LDS write->read (own slot only): compiler-inserted lgkmcnt
    // orders it; no cross-wave dependency so no __syncthreads needed.

    if (valid) {
        float c0 = b1[lane], c1 = b2[lane], c2 = 0.f, c3 = 0.f;
#pragma unroll
        for (int q = 0; q < 16; q++) {
            float4 h1v = hbuf[wave][q].h1;   // uniform -> broadcast, conflict-free
            float4 h2v = hbuf[wave][q].h2;
#pragma unroll
            for (int c = 0; c < 4; c += 2) {
                float2 wa = wB[((q * 4 + c) << 6) + lane];
                float2 wb = wB[((q * 4 + c + 1) << 6) + lane];
                float ha0 = (&h1v.x)[c], hb0 = (&h2v.x)[c];
                float ha1 = (&h1v.x)[c + 1], hb1 = (&h2v.x)[c + 1];
                c0 = fmaf(ha0, wa.x, c0);
                c1 = fmaf(hb0, wa.y, c1);
                c2 = fmaf(ha1, wb.x, c2);
                c3 = fmaf(hb1, wb.y, c3);
            }
        }
        out[(i << 6) + lane] = (c0 + c2) + (c1 + c3);
    }
}

extern "C" void kernel_launch(void* const* d_in, const int* in_sizes, int n_in,
                              void* d_out, int out_size, void* d_ws, size_t ws_size,
                              hipStream_t stream) {
    const float* embed = (const float*)d_in[0];
    const int* row = (const int*)d_in[1];
    const int* col = (const int*)d_in[2];
    const float* W1 = (const float*)d_in[3];
    const float* b1 = (const float*)d_in[4];
    const float* W2 = (const float*)d_in[5];
    const float* b2 = (const float*)d_in[6];
    float* out = (float*)d_out;

    int n = in_sizes[0] / 64;   // 144242
    int E = in_sizes[1];        // 2,000,000
    int nblk = (n + 1023) / 1024;

    char* ws = (char*)d_ws;
    size_t off = 0;
    // 8B-aligned buffers first
    int2* sedge = (int2*)(ws + off);  off += (size_t)E * 8;
    float2* wBg = (float2*)(ws + off); off += 4096 * 8;
    int* deg = (int*)(ws + off);      off += (size_t)n * 4;
    float* dinv = (float*)(ws + off); off += (size_t)n * 4;
    int* part = (int*)(ws + off);     off += (size_t)n * 4;
    int* bsums = (int*)(ws + off);    off += (size_t)(nblk + 1) * 4;
    int* start = (int*)(ws + off);    off += (size_t)(n + 1) * 4;
    int* cursor = (int*)(ws + off);   off += (size_t)n * 4;

    if (off > ws_size) return;  // ws too small -> out stays zero (0.707 absmax signal)

    hipMemsetAsync(deg, 0, (size_t)n * 4, stream);
    k_deg<<<(E + 255) / 256, 256, 0, stream>>>(row, deg, E);
    k_dinv_wprep<<<(n + 255) / 256, 256, 0, stream>>>(deg, dinv, W1, W2, wBg, n);
    k_scan1<<<nblk, 256, 0, stream>>>(deg, part, bsums, n);
    k_scan2<<<1, 64, 0, stream>>>(bsums, nblk);
    k_scan3<<<(n + 255) / 256, 256, 0, stream>>>(part, bsums, start, cursor, n, E);
    k_fill<<<(E + 255) / 256, 256, 0, stream>>>(row, col, dinv, cursor, sedge, E);
    k_main<<<(n + 7) / 8, 512, 0, stream>>>((const float4*)embed, start, sedge,
                                            wBg, b1, b2, out, n);
}